// Round 10
// baseline (191.726 us; speedup 1.0000x reference)
//
#include <hip/hip_runtime.h>

#define BTOT 8192
#define TT 512
#define LOG2E 1.44269504089f

__device__ __forceinline__ float rcp_f(float x)  { return __builtin_amdgcn_rcpf(x); }
__device__ __forceinline__ float exp2_f(float x) { return __builtin_amdgcn_exp2f(x); }
__device__ __forceinline__ float bperm(int addr4, float v) {
    return __int_as_float(__builtin_amdgcn_ds_bpermute(addr4, __float_as_int(v)));
}
template<int CTRL>
__device__ __forceinline__ float qb(float v) {   // quad_perm broadcast
    return __int_as_float(__builtin_amdgcn_mov_dpp(__float_as_int(v), CTRL, 0xf, 0xf, true));
}

__global__ __launch_bounds__(64) void lstm_kernel(
    const float* __restrict__ x,
    const float* __restrict__ W_ih,
    const float* __restrict__ W_hh,
    const float* __restrict__ b_ih,
    const float* __restrict__ b_hh,
    const float* __restrict__ fc1_w,
    const float* __restrict__ fc1_b,
    const float* __restrict__ fc2_w,
    const float* __restrict__ fc2_b,
    float* __restrict__ out)
{
    const int lane   = threadIdx.x;                 // one wave per block
    const int ll     = (lane < 60) ? lane : 59;     // idle lanes alias lane 59 (read-only)
    const int bw     = ll / 20;                     // group: 0..2
    const int within = ll % 20;
    const int j      = within >> 2;                 // hidden unit (quad index)
    const int g      = within & 3;                  // gate (0=i,1=f,2=g,3=o)
    const int base   = bw * 20;                     // 0/20/40, 4-aligned for quad_perm

    // each group time-interleaves TWO batches
    const int bA_raw = blockIdx.x * 6 + bw * 2;
    const int bB_raw = bA_raw + 1;
    const int bA = (bA_raw < BTOT) ? bA_raw : (BTOT - 1);
    const int bB = (bB_raw < BTOT) ? bB_raw : (BTOT - 1);

    // fold activation scaling (incl log2e) into weights (R6 math, proven):
    //  i,f,o: acc = -z*log2e -> sigmoid(z) =     rcp(1+exp2(acc))
    //  g    : acc = 2z*log2e -> tanh(z)    = 1 - 2*rcp(1+exp2(acc))
    const float sc   = (g == 2) ? (2.0f * LOG2E) : (-LOG2E);
    const float selA = (g == 2) ? -2.0f :  1.0f;
    const float selB = (g == 2) ?  1.0f :  0.0f;

    const int row = g * 5 + j;                      // PyTorch gate-major row
    float wih[5], whh[5];
    #pragma unroll
    for (int i = 0; i < 5; ++i) {
        wih[i] = sc * W_ih[row * 5 + i];
        whh[i] = sc * W_hh[row * 5 + i];
    }
    const float bias_s = sc * (b_ih[row] + b_hh[row]);

    // h_k replicated across quad k; gather from quad-base lanes
    int a_h[5];
    #pragma unroll
    for (int k = 0; k < 5; ++k) a_h[k] = (base + 4 * k) << 2;

    const float* xA = x + (size_t)bA * (TT * 5);
    const float* xB = x + (size_t)bB * (TT * 5);

    float hvA[5] = {0.f, 0.f, 0.f, 0.f, 0.f};
    float hvB[5] = {0.f, 0.f, 0.f, 0.f, 0.f};
    float CA = 0.f, CB = 0.f;

    float4 bufA[5], bufB[5];
    #pragma unroll
    for (int i = 0; i < 5; ++i) {
        bufA[i] = *(const float4*)(xA + 4 * i);     // batch A, t = 0..3
        bufB[i] = *(const float4*)(xB + 4 * i);     // batch B, t = 0..3
    }

    // component of a 5-float4 buffer at flat index (compile-time)
    auto bufAt = [](const float4* buf, int idx) -> float {
        const float4 v = buf[idx >> 2];
        switch (idx & 3) {
            case 0: return v.x;
            case 1: return v.y;
            case 2: return v.z;
            default: return v.w;
        }
    };

    for (int t0 = 0; t0 < TT; t0 += 4) {
        // x-projections for 4 steps, both batches (consumes bufs)
        float gxA[4], gxB[4];
        #pragma unroll
        for (int s = 0; s < 4; ++s) {
            float aA = bias_s, aB = bias_s;
            #pragma unroll
            for (int i = 0; i < 5; ++i) {
                aA = fmaf(wih[i], bufAt(bufA, s * 5 + i), aA);
                aB = fmaf(wih[i], bufAt(bufB, s * 5 + i), aB);
            }
            gxA[s] = aA; gxB[s] = aB;
        }

        // refill both buffers for t0+4 (in flight across the 4 step-pairs)
        {
            const int tld = (t0 + 4 <= TT - 4) ? (t0 + 4) : (TT - 4);
            const float* pA = xA + tld * 5;
            const float* pB = xB + tld * 5;
            #pragma unroll
            for (int i = 0; i < 5; ++i) {
                bufA[i] = *(const float4*)(pA + 4 * i);
                bufB[i] = *(const float4*)(pB + 4 * i);
            }
        }

        #pragma unroll
        for (int s = 0; s < 4; ++s) {
            // ---- batch A step (its bperm latency is covered by B's step) ----
            {
                float acc = gxA[s];
                #pragma unroll
                for (int k = 0; k < 5; ++k) acc = fmaf(whh[k], hvA[k], acc);
                const float val = fmaf(selA, rcp_f(1.0f + exp2_f(acc)), selB);
                const float iv = qb<0x00>(val);
                const float fv = qb<0x55>(val);
                const float gv = qb<0xAA>(val);
                const float ov = qb<0xFF>(val);
                CA = fmaf(fv, CA, iv * gv);
                const float ec = exp2_f(CA * (2.0f * LOG2E));
                const float h  = ov * fmaf(-2.0f, rcp_f(1.0f + ec), 1.0f);
                #pragma unroll
                for (int k = 0; k < 5; ++k) hvA[k] = bperm(a_h[k], h);
            }
            // ---- batch B step (covers A's wait; its own wait covered by next A) ----
            {
                float acc = gxB[s];
                #pragma unroll
                for (int k = 0; k < 5; ++k) acc = fmaf(whh[k], hvB[k], acc);
                const float val = fmaf(selA, rcp_f(1.0f + exp2_f(acc)), selB);
                const float iv = qb<0x00>(val);
                const float fv = qb<0x55>(val);
                const float gv = qb<0xAA>(val);
                const float ov = qb<0xFF>(val);
                CB = fmaf(fv, CB, iv * gv);
                const float ec = exp2_f(CB * (2.0f * LOG2E));
                const float h  = ov * fmaf(-2.0f, rcp_f(1.0f + ec), 1.0f);
                #pragma unroll
                for (int k = 0; k < 5; ++k) hvB[k] = bperm(a_h[k], h);
            }
        }
    }

    // final h replicated across each group for both batches
    if (lane < 60) {
        if (within == 0 && bA_raw < BTOT) {
            float p = fc1_b[0];
            float v = fc2_b[0];
            #pragma unroll
            for (int k = 0; k < 5; ++k) {
                p = fmaf(fc1_w[k], hvA[k], p);
                v = fmaf(fc2_w[k], hvA[k], v);
            }
            out[bA] = p;
            out[BTOT + bA] = v;
        }
        if (within == 1 && bB_raw < BTOT) {
            float p = fc1_b[0];
            float v = fc2_b[0];
            #pragma unroll
            for (int k = 0; k < 5; ++k) {
                p = fmaf(fc1_w[k], hvB[k], p);
                v = fmaf(fc2_w[k], hvB[k], v);
            }
            out[bB] = p;
            out[BTOT + bB] = v;
        }
    }
}

extern "C" void kernel_launch(void* const* d_in, const int* in_sizes, int n_in,
                              void* d_out, int out_size, void* d_ws, size_t ws_size,
                              hipStream_t stream) {
    const float* x     = (const float*)d_in[0];
    const float* W_ih  = (const float*)d_in[1];
    const float* W_hh  = (const float*)d_in[2];
    const float* b_ih  = (const float*)d_in[3];
    const float* b_hh  = (const float*)d_in[4];
    const float* fc1_w = (const float*)d_in[5];
    const float* fc1_b = (const float*)d_in[6];
    const float* fc2_w = (const float*)d_in[7];
    const float* fc2_b = (const float*)d_in[8];
    float* out = (float*)d_out;

    const int blocks = (BTOT + 5) / 6;   // 1366 one-wave blocks, 6 batches each (3 groups x 2)
    lstm_kernel<<<blocks, 64, 0, stream>>>(x, W_ih, W_hh, b_ih, b_hh,
                                           fc1_w, fc1_b, fc2_w, fc2_b, out);
}

// Round 11
// 162.322 us; speedup vs baseline: 1.1811x; 1.1811x over previous
//
#include <hip/hip_runtime.h>

#define BTOT 8192
#define TT 512

// soft reciprocal: magic seed + 2 Newton -> ~1e-6 rel err, all-VALU, dep depth ~20cy
__device__ __forceinline__ float srcp(float d) {
    float r = __int_as_float(0x7EF311C3 - __float_as_int(d));
    r = r * fmaf(-d, r, 2.0f);
    r = r * fmaf(-d, r, 2.0f);
    return r;
}

// tanh Pade[7/6]: tanh(t) ~ t*(135135+17325u+378u^2+u^3)/(135135+62370u+3150u^2+28u^3)
// err <= 2e-5 on [-4,4], ~1e-4 at the +-5 clamp edge. Proven at bf16 floor in R8/R9.
__device__ __forceinline__ void tanh_parts(float t, float& num, float& den) {
    const float u = t * t;
    float np = u + 378.0f;
    np = fmaf(np, u, 17325.0f);
    np = fmaf(np, u, 135135.0f);
    num = t * np;
    float dp = fmaf(28.0f, u, 3150.0f);
    dp = fmaf(dp, u, 62370.0f);
    den = fmaf(dp, u, 135135.0f);
}

// DPP row shifts, empirically validated in R5 (passed at bf16 floor):
//   ctrl 0x100+m : dst[i] = src[i+m]   (valid while i%16+m <= 15)
//   ctrl 0x110+m : dst[i] = src[i-m]   (valid while i%16-m >= 0)
// bound_ctrl=true -> out-of-bounds lanes read 0 (always killed by zero weights).
template<int CTRL>
__device__ __forceinline__ float dppf(float v) {
    return __int_as_float(__builtin_amdgcn_mov_dpp(__float_as_int(v), CTRL, 0xf, 0xf, true));
}

__global__ __launch_bounds__(64) void lstm_kernel(
    const float* __restrict__ x,
    const float* __restrict__ W_ih,
    const float* __restrict__ W_hh,
    const float* __restrict__ b_ih,
    const float* __restrict__ b_hh,
    const float* __restrict__ fc1_w,
    const float* __restrict__ fc1_b,
    const float* __restrict__ fc2_w,
    const float* __restrict__ fc2_b,
    float* __restrict__ out)
{
    const int lane  = threadIdx.x;            // one wave per block
    const int u_raw = lane & 7;               // slot within octet
    const int u     = (u_raw < 5) ? u_raw : 0; // pad lanes alias unit 0 (finite, never read)
    const int b     = blockIdx.x * 8 + (lane >> 3);   // 1024*8 = 8192 exact
    const bool wr   = (u_raw == 0);

    // Lane owns all 4 gate rows of unit u.  sigmoid(z)=0.5+0.5*tanh(z/2):
    // fold the 0.5 into i,f,o weights; g-gate (r==2) keeps scale 1 -> tanh.
    float wih[4][5], bias[4];
    float wp[4][9];   // recurrent weights by shift d=k-u (d+4 index), zero-padded
    #pragma unroll
    for (int r = 0; r < 4; ++r) {
        const float s = (r == 2) ? 1.0f : 0.5f;
        const int row = r * 5 + u;            // PyTorch gate-major
        #pragma unroll
        for (int i = 0; i < 5; ++i) wih[r][i] = s * W_ih[row * 5 + i];
        bias[r] = s * (b_ih[row] + b_hh[row]);
        #pragma unroll
        for (int d = -4; d <= 4; ++d) {
            const int k = u + d;
            wp[r][d + 4] = (k >= 0 && k <= 4) ? s * W_hh[row * 5 + k] : 0.0f;
        }
    }

    const float* xb = x + (size_t)b * (TT * 5);

    float h = 0.0f, C = 0.0f;

    float4 bufA[5], bufB[5];
    #pragma unroll
    for (int i = 0; i < 5; ++i) {
        bufA[i] = *(const float4*)(xb + 0  + 4 * i);   // t = 0..3
        bufB[i] = *(const float4*)(xb + 20 + 4 * i);   // t = 4..7
    }

    auto process4 = [&](const float4* buf) {
        float xs[20];
        *(float4*)&xs[0]  = buf[0];
        *(float4*)&xs[4]  = buf[1];
        *(float4*)&xs[8]  = buf[2];
        *(float4*)&xs[12] = buf[3];
        *(float4*)&xs[16] = buf[4];

        // x-projections for 4 steps x 4 gates up-front (big independent ILP block)
        float gx[4][4];
        #pragma unroll
        for (int s = 0; s < 4; ++s)
            #pragma unroll
            for (int r = 0; r < 4; ++r) {
                float a = bias[r];
                #pragma unroll
                for (int i = 0; i < 5; ++i) a = fmaf(wih[r][i], xs[s * 5 + i], a);
                gx[s][r] = a;
            }

        #pragma unroll
        for (int s = 0; s < 4; ++s) {
            // 8 DPP shifts of h, shared by all 4 gate dots (no LDS anywhere)
            const float sp1 = dppf<0x101>(h);
            const float sp2 = dppf<0x102>(h);
            const float sp3 = dppf<0x103>(h);
            const float sp4 = dppf<0x104>(h);
            const float sm1 = dppf<0x111>(h);
            const float sm2 = dppf<0x112>(h);
            const float sm3 = dppf<0x113>(h);
            const float sm4 = dppf<0x114>(h);

            // recurrent dots: z_r = gx + sum_d wp[r][d]*shift_d(h)
            float z[4];
            #pragma unroll
            for (int r = 0; r < 4; ++r) {
                float a = gx[s][r];
                a = fmaf(wp[r][0], sm4, a);
                a = fmaf(wp[r][1], sm3, a);
                a = fmaf(wp[r][2], sm2, a);
                a = fmaf(wp[r][3], sm1, a);
                a = fmaf(wp[r][4], h,   a);
                a = fmaf(wp[r][5], sp1, a);
                a = fmaf(wp[r][6], sp2, a);
                a = fmaf(wp[r][7], sp3, a);
                a = fmaf(wp[r][8], sp4, a);
                z[r] = a;
            }

            // 4 activations, fully parallel Pade sites
            float val[4];
            #pragma unroll
            for (int r = 0; r < 4; ++r) {
                const float t = __builtin_amdgcn_fmed3f(z[r], -5.0f, 5.0f);
                float num, den;
                tanh_parts(t, num, den);
                const float rr = srcp(den);
                if (r == 2) val[r] = num * rr;                         // tanh(z)
                else        val[r] = fmaf(0.5f, num, 0.5f * den) * rr; // sigmoid
            }

            // cell update + output tanh (the only serial segment)
            C = fmaf(val[1], C, val[0] * val[2]);
            const float t2 = __builtin_amdgcn_fmed3f(C, -5.0f, 5.0f);
            float num2, den2;
            tanh_parts(t2, num2, den2);
            h = val[3] * (num2 * srcp(den2));   // lane u now holds h_u
        }
    };

    for (int t0 = 0; t0 < TT; t0 += 8) {
        process4(bufA);                                // steps t0 .. t0+3
        {
            const int tld = (t0 + 8 <= TT - 4) ? (t0 + 8) : (TT - 4);
            const float* p = xb + tld * 5;
            #pragma unroll
            for (int i = 0; i < 5; ++i) bufA[i] = *(const float4*)(p + 4 * i);
        }
        process4(bufB);                                // steps t0+4 .. t0+7
        {
            const int tld = (t0 + 12 <= TT - 4) ? (t0 + 12) : (TT - 4);
            const float* p = xb + tld * 5;
            #pragma unroll
            for (int i = 0; i < 5; ++i) bufB[i] = *(const float4*)(p + 4 * i);
        }
    }

    // gather h_1..h_4 onto the u==0 lane (reads +1..+4, all in-row valid)
    const float g1 = dppf<0x101>(h);
    const float g2 = dppf<0x102>(h);
    const float g3 = dppf<0x103>(h);
    const float g4 = dppf<0x104>(h);

    if (wr) {
        float p = fc1_b[0];
        float v = fc2_b[0];
        p = fmaf(fc1_w[0], h,  p);  v = fmaf(fc2_w[0], h,  v);
        p = fmaf(fc1_w[1], g1, p);  v = fmaf(fc2_w[1], g1, v);
        p = fmaf(fc1_w[2], g2, p);  v = fmaf(fc2_w[2], g2, v);
        p = fmaf(fc1_w[3], g3, p);  v = fmaf(fc2_w[3], g3, v);
        p = fmaf(fc1_w[4], g4, p);  v = fmaf(fc2_w[4], g4, v);
        out[b] = p;
        out[BTOT + b] = v;
    }
}

extern "C" void kernel_launch(void* const* d_in, const int* in_sizes, int n_in,
                              void* d_out, int out_size, void* d_ws, size_t ws_size,
                              hipStream_t stream) {
    const float* x     = (const float*)d_in[0];
    const float* W_ih  = (const float*)d_in[1];
    const float* W_hh  = (const float*)d_in[2];
    const float* b_ih  = (const float*)d_in[3];
    const float* b_hh  = (const float*)d_in[4];
    const float* fc1_w = (const float*)d_in[5];
    const float* fc1_b = (const float*)d_in[6];
    const float* fc2_w = (const float*)d_in[7];
    const float* fc2_b = (const float*)d_in[8];
    float* out = (float*)d_out;

    const int blocks = BTOT / 8;   // 1024 one-wave blocks, 8 batches each -> K=1, every SIMD busy
    lstm_kernel<<<blocks, 64, 0, stream>>>(x, W_ih, W_hh, b_ih, b_hh,
                                           fc1_w, fc1_b, fc2_w, fc2_b, out);
}

// Round 12
// 123.587 us; speedup vs baseline: 1.5513x; 1.3134x over previous
//
#include <hip/hip_runtime.h>

#define BTOT 8192
#define TT 512
#define LOG2E 1.44269504089f

__device__ __forceinline__ float exp2_f(float x) { return __builtin_amdgcn_exp2f(x); }
__device__ __forceinline__ float bperm(int addr4, float v) {
    return __int_as_float(__builtin_amdgcn_ds_bpermute(addr4, __float_as_int(v)));
}
template<int CTRL>
__device__ __forceinline__ float qb(float v) {   // quad_perm broadcast
    return __int_as_float(__builtin_amdgcn_mov_dpp(__float_as_int(v), CTRL, 0xf, 0xf, true));
}
// soft reciprocal: magic seed + 2 Newton -> ~1e-6 rel err. Dep depth ~25 cy
// (vs v_rcp_f32 ~100). Valid for normal-range d>0; inputs clamped upstream.
__device__ __forceinline__ float srcp(float d) {
    float r = __int_as_float(0x7EF311C3 - __float_as_int(d));
    r = r * fmaf(-d, r, 2.0f);
    r = r * fmaf(-d, r, 2.0f);
    return r;
}

__global__ __launch_bounds__(64) void lstm_kernel(
    const float* __restrict__ x,
    const float* __restrict__ W_ih,
    const float* __restrict__ W_hh,
    const float* __restrict__ b_ih,
    const float* __restrict__ b_hh,
    const float* __restrict__ fc1_w,
    const float* __restrict__ fc1_b,
    const float* __restrict__ fc2_w,
    const float* __restrict__ fc2_b,
    float* __restrict__ out)
{
    const int lane   = threadIdx.x;                 // one wave per block
    const int ll     = (lane < 60) ? lane : 59;     // idle lanes alias lane 59
    const int bw     = ll / 20;                     // batch within wave: 0..2
    const int within = ll % 20;                     // row slot within batch group
    const int j      = within >> 2;                 // hidden unit (quad index, 0..4)
    const int g      = within & 3;                  // gate (0=i,1=f,2=g,3=o)
    const int base   = bw * 20;                     // group base lane (0/20/40, 4-aligned)
    const int b_raw  = blockIdx.x * 3 + bw;
    const bool write_ok = (lane < 60) && (within == 0) && (b_raw < BTOT);
    const int b = (b_raw < BTOT) ? b_raw : (BTOT - 1);

    // fold activation scaling (incl log2e for raw exp2) into weights:
    //  i,f,o: acc = -z*log2e -> sigmoid(z) =     srcp(1+exp2(acc))
    //  g    : acc = 2z*log2e -> tanh(z)    = 1 - 2*srcp(1+exp2(acc))
    const float sc   = (g == 2) ? (2.0f * LOG2E) : (-LOG2E);
    const float selA = (g == 2) ? -2.0f :  1.0f;
    const float selB = (g == 2) ?  1.0f :  0.0f;

    const int row = g * 5 + j;                      // PyTorch gate-major row
    float wih[5], whh[5];
    #pragma unroll
    for (int i = 0; i < 5; ++i) {
        wih[i] = sc * W_ih[row * 5 + i];
        whh[i] = sc * W_hh[row * 5 + i];
    }
    const float bias_s = sc * (b_ih[row] + b_hh[row]);

    // h_k replicated across quad k; gather from quad-base lanes
    int a_h[5];
    #pragma unroll
    for (int k = 0; k < 5; ++k) a_h[k] = (base + 4 * k) << 2;

    const float* xb = x + (size_t)b * (TT * 5);

    float hv[5] = {0.f, 0.f, 0.f, 0.f, 0.f};
    float c = 0.f;

    float4 bufA[5], bufB[5];
    #pragma unroll
    for (int i = 0; i < 5; ++i) {
        bufA[i] = *(const float4*)(xb + 0  + 4 * i);   // t = 0..3
        bufB[i] = *(const float4*)(xb + 20 + 4 * i);   // t = 4..7
    }

    auto process4 = [&](const float4* buf) {
        float xs[20];
        *(float4*)&xs[0]  = buf[0];
        *(float4*)&xs[4]  = buf[1];
        *(float4*)&xs[8]  = buf[2];
        *(float4*)&xs[12] = buf[3];
        *(float4*)&xs[16] = buf[4];

        auto proj = [&](int s) {
            float a = bias_s;
            #pragma unroll
            for (int i = 0; i < 5; ++i) a = fmaf(wih[i], xs[s * 5 + i], a);
            return a;
        };

        float gxc = proj(0);
        #pragma unroll
        for (int s = 0; s < 4; ++s) {
            // recurrent dot as a tree (shorter dep chain than serial fma)
            const float m0 = fmaf(whh[0], hv[0], gxc);
            const float m1 = fmaf(whh[1], hv[1], whh[2] * hv[2]);
            const float m2 = fmaf(whh[3], hv[3], whh[4] * hv[4]);
            const float acc = (m0 + m1) + m2;

            // activation: hw exp2 (cheap issue) + soft reciprocal (short latency)
            const float ta  = __builtin_amdgcn_fmed3f(acc, -30.0f, 30.0f);
            const float E1  = exp2_f(ta);
            const float val = fmaf(selA, srcp(1.0f + E1), selB);

            // unit j's 4 gates live in this quad: 4 DPP broadcasts
            const float iv = qb<0x00>(val);
            const float fv = qb<0x55>(val);
            const float gv = qb<0xAA>(val);
            const float ov = qb<0xFF>(val);

            // cell update + output tanh via exp2 + soft rcp
            c = fmaf(fv, c, iv * gv);
            const float tc = __builtin_amdgcn_fmed3f(c * (2.0f * LOG2E), -30.0f, 30.0f);
            const float E2 = exp2_f(tc);
            const float h  = ov * fmaf(-2.0f, srcp(1.0f + E2), 1.0f);

            // single LDS round: gather h_0..h_4 from quad-base lanes
            #pragma unroll
            for (int k = 0; k < 5; ++k) hv[k] = bperm(a_h[k], h);

            // fill the bperm shadow with next step's x-projection
            if (s < 3) gxc = proj(s + 1);
        }
    };

    for (int t0 = 0; t0 < TT; t0 += 8) {
        process4(bufA);                                // steps t0 .. t0+3
        {
            const int tld = (t0 + 8 <= TT - 4) ? (t0 + 8) : (TT - 4);
            const float* p = xb + tld * 5;
            #pragma unroll
            for (int i = 0; i < 5; ++i) bufA[i] = *(const float4*)(p + 4 * i);
        }
        process4(bufB);                                // steps t0+4 .. t0+7
        {
            const int tld = (t0 + 12 <= TT - 4) ? (t0 + 12) : (TT - 4);
            const float* p = xb + tld * 5;
            #pragma unroll
            for (int i = 0; i < 5; ++i) bufB[i] = *(const float4*)(p + 4 * i);
        }
    }

    // hv holds the final hidden state on every lane
    if (write_ok) {
        float p = fc1_b[0];
        float v = fc2_b[0];
        #pragma unroll
        for (int k = 0; k < 5; ++k) {
            p = fmaf(fc1_w[k], hv[k], p);
            v = fmaf(fc2_w[k], hv[k], v);
        }
        out[b] = p;
        out[BTOT + b] = v;
    }
}

extern "C" void kernel_launch(void* const* d_in, const int* in_sizes, int n_in,
                              void* d_out, int out_size, void* d_ws, size_t ws_size,
                              hipStream_t stream) {
    const float* x     = (const float*)d_in[0];
    const float* W_ih  = (const float*)d_in[1];
    const float* W_hh  = (const float*)d_in[2];
    const float* b_ih  = (const float*)d_in[3];
    const float* b_hh  = (const float*)d_in[4];
    const float* fc1_w = (const float*)d_in[5];
    const float* fc1_b = (const float*)d_in[6];
    const float* fc2_w = (const float*)d_in[7];
    const float* fc2_b = (const float*)d_in[8];
    float* out = (float*)d_out;

    const int blocks = (BTOT + 2) / 3;   // 2731 one-wave blocks, 3 batches each
    lstm_kernel<<<blocks, 64, 0, stream>>>(x, W_ih, W_hh, b_ih, b_hh,
                                           fc1_w, fc1_b, fc2_w, fc2_b, out);
}